// Round 1
// baseline (1792.663 us; speedup 1.0000x reference)
//
#include <hip/hip_runtime.h>

// ct_layer: 5x conv3x3(+BN affine folded) + corner pools on MI355X.
// Key identity: reverse-cummax then forward-cummax == global max broadcast.
//
// Pipeline (all fp16 storage, fp32 MFMA accumulate):
//   memset(x_pad,s_pad,relu_pad = 0)            -- zero borders = SAME padding
//   k_pack_x      : x NCHW f32 -> x_pad NHWC f16 [8][98][98][256]
//   k_repack_w    : 5x (w*g) OIHW f32 -> [co][tap][ci] f16
//   k_conv_p12    : p1 = relu(conv(x,w_p1)+b1), p2 = ... (gridDim.z=2), NHWC f16
//   k_reduce_h/w  : u[b][w][c] = max_h p1 ; v[b][h][c] = max_w p2
//   k_build_s     : s_pad interior = f16(u+v)
//   k_conv_pc1    : relu_pad = relu(conv(s,w_p)+b_p + conv(x,w_c1)+b_c1)  (fused)
//   k_conv_c2     : d_out = relu(conv(relu_pad,w_c2)+b_c2)  NCHW f32

typedef _Float16 f16x8 __attribute__((ext_vector_type(8)));
typedef _Float16 f16x4v __attribute__((ext_vector_type(4)));
typedef float f32x4 __attribute__((ext_vector_type(4)));

#define CIN   256
#define CH    256
#define HH    96
#define WWD   96
#define BB    8
#define HP    98
#define WP    98
#define KTOT  2304                     // 256*9
#define NTOT  (BB*HH*WWD)              // 73728
#define WSET  (CH*KTOT)                // 589824 elems per weight set
#define XPAD_E ((size_t)BB*HP*WP*CIN)  // 19,668,992 elems
#define PBUF_E ((size_t)NTOT*CH)       // 18,874,368 elems
#define UV_E   (BB*WWD*CH)             // 196,608 elems

// ---------------- implicit-GEMM core: wave computes 64co x 64n -------------
// A (weights) fragment: lane holds A[m=l16][k=quad*8+j] -> one 16B load
// B (input)   fragment: lane holds B[k=quad*8+j][n=l16] -> one 16B load
__device__ __forceinline__ void conv_gemm(const _Float16* __restrict__ xp,
                                          const _Float16* __restrict__ wk,
                                          const unsigned sbase[4],
                                          const unsigned abase[4],
                                          f32x4 acc[4][4])
{
#pragma unroll 1
  for (int dhw = 0; dhw < 9; ++dhw) {
    const int dh = dhw / 3, dw = dhw - dh * 3;
    const unsigned aoff0 = (unsigned)dhw * 256u;
    const unsigned boff0 = (unsigned)(dh * WP + dw) * 256u;
#pragma unroll
    for (int cb = 0; cb < 8; ++cb) {
      const unsigned ao = aoff0 + cb * 32u;
      const unsigned bo = boff0 + cb * 32u;
      f16x8 af[4], bf[4];
#pragma unroll
      for (int i = 0; i < 4; ++i) af[i] = *(const f16x8*)(wk + abase[i] + ao);
#pragma unroll
      for (int i = 0; i < 4; ++i) bf[i] = *(const f16x8*)(xp + sbase[i] + bo);
#pragma unroll
      for (int i = 0; i < 4; ++i)
#pragma unroll
        for (int j = 0; j < 4; ++j)
          acc[i][j] = __builtin_amdgcn_mfma_f32_16x16x32_f16(af[i], bf[j], acc[i][j], 0, 0, 0);
    }
  }
}

// Common per-wave setup. Decode per-lane bases once (n fixed for whole K loop).
__device__ __forceinline__ void conv_setup(int co_wg, int n_wg, unsigned abase[4],
                                           unsigned sbase[4], int& co_wv, int& n_wv,
                                           int& quad, int& l16)
{
  const int lane = threadIdx.x & 63;
  const int wv   = threadIdx.x >> 6;
  quad = lane >> 4; l16 = lane & 15;
  co_wv = (wv & 1) * 64;
  n_wv  = (wv >> 1) * 64;
#pragma unroll
  for (int i = 0; i < 4; ++i) {
    int co = co_wg + co_wv + i * 16 + l16;
    abase[i] = (unsigned)co * KTOT + quad * 8;
  }
#pragma unroll
  for (int i = 0; i < 4; ++i) {
    int n = n_wg + n_wv + i * 16 + l16;
    int b = n / 9216; int r = n - b * 9216;
    int h = r / 96;   int w = r - h * 96;
    sbase[i] = ((unsigned)(b * HP + h) * WP + (unsigned)w) * 256u + quad * 8;
  }
}

// ---------------- conv kernel 1: p1/p2 branches (relu), NHWC f16 out -------
__global__ __launch_bounds__(256, 2) void k_conv_p12(
    const _Float16* __restrict__ xpad, const _Float16* __restrict__ wk,
    const float* __restrict__ bias1, const float* __restrict__ bias2,
    _Float16* __restrict__ p1, _Float16* __restrict__ p2)
{
  const int branch = blockIdx.z;
  const _Float16* w = wk + (size_t)branch * WSET;
  const float* bias = branch ? bias2 : bias1;
  _Float16* out = branch ? p2 : p1;
  const int co_wg = blockIdx.x * 128;
  const int n_wg  = blockIdx.y * 128;

  unsigned abase[4], sbase[4]; int co_wv, n_wv, quad, l16;
  conv_setup(co_wg, n_wg, abase, sbase, co_wv, n_wv, quad, l16);

  f32x4 acc[4][4];
#pragma unroll
  for (int i = 0; i < 4; ++i)
#pragma unroll
    for (int j = 0; j < 4; ++j) acc[i][j] = (f32x4){0.f, 0.f, 0.f, 0.f};

  conv_gemm(xpad, w, sbase, abase, acc);

  // epilogue: bias+relu -> LDS transpose [n][co] -> coalesced NHWC writes
  __shared__ _Float16 lt[128 * 132];
#pragma unroll
  for (int fa = 0; fa < 4; ++fa) {
    const int co_l = co_wv + fa * 16 + quad * 4;
    const float4 bs = *(const float4*)(bias + co_wg + co_l);
#pragma unroll
    for (int fb = 0; fb < 4; ++fb) {
      const int n_l = n_wv + fb * 16 + l16;
      f16x4v pk;
      pk[0] = (_Float16)fmaxf(acc[fa][fb][0] + bs.x, 0.f);
      pk[1] = (_Float16)fmaxf(acc[fa][fb][1] + bs.y, 0.f);
      pk[2] = (_Float16)fmaxf(acc[fa][fb][2] + bs.z, 0.f);
      pk[3] = (_Float16)fmaxf(acc[fa][fb][3] + bs.w, 0.f);
      *(f16x4v*)&lt[n_l * 132 + co_l] = pk;
    }
  }
  __syncthreads();
  const int cc = threadIdx.x & 15, rr = threadIdx.x >> 4;
#pragma unroll
  for (int pass = 0; pass < 8; ++pass) {
    const int n_l = pass * 16 + rr;
    const int n = n_wg + n_l;
    uint2 q0 = *(const uint2*)&lt[n_l * 132 + cc * 8];
    uint2 q1 = *(const uint2*)&lt[n_l * 132 + cc * 8 + 4];
    *(uint4*)(out + (size_t)n * 256 + co_wg + cc * 8) = make_uint4(q0.x, q0.y, q1.x, q1.y);
  }
}

// ---------------- conv kernel 3: fused conv_p(s) + conv_c1(x), relu --------
__global__ __launch_bounds__(256, 2) void k_conv_pc1(
    const _Float16* __restrict__ spad, const _Float16* __restrict__ xpad,
    const _Float16* __restrict__ wp, const _Float16* __restrict__ wc1,
    const float* __restrict__ bias_p, const float* __restrict__ bias_c1,
    _Float16* __restrict__ rpad)
{
  const int co_wg = blockIdx.x * 128;
  const int n_wg  = blockIdx.y * 128;
  unsigned abase[4], sbase[4]; int co_wv, n_wv, quad, l16;
  conv_setup(co_wg, n_wg, abase, sbase, co_wv, n_wv, quad, l16);

  f32x4 acc[4][4];
#pragma unroll
  for (int i = 0; i < 4; ++i)
#pragma unroll
    for (int j = 0; j < 4; ++j) acc[i][j] = (f32x4){0.f, 0.f, 0.f, 0.f};

  conv_gemm(spad, wp,  sbase, abase, acc);   // p_conv
  conv_gemm(xpad, wc1, sbase, abase, acc);   // + conv1 (same GEMM geometry)

  __shared__ _Float16 lt[128 * 132];
#pragma unroll
  for (int fa = 0; fa < 4; ++fa) {
    const int co_l = co_wv + fa * 16 + quad * 4;
    const float4 b1 = *(const float4*)(bias_p + co_wg + co_l);
    const float4 b2 = *(const float4*)(bias_c1 + co_wg + co_l);
#pragma unroll
    for (int fb = 0; fb < 4; ++fb) {
      const int n_l = n_wv + fb * 16 + l16;
      f16x4v pk;
      pk[0] = (_Float16)fmaxf(acc[fa][fb][0] + b1.x + b2.x, 0.f);
      pk[1] = (_Float16)fmaxf(acc[fa][fb][1] + b1.y + b2.y, 0.f);
      pk[2] = (_Float16)fmaxf(acc[fa][fb][2] + b1.z + b2.z, 0.f);
      pk[3] = (_Float16)fmaxf(acc[fa][fb][3] + b1.w + b2.w, 0.f);
      *(f16x4v*)&lt[n_l * 132 + co_l] = pk;
    }
  }
  __syncthreads();
  const int cc = threadIdx.x & 15, rr = threadIdx.x >> 4;
#pragma unroll
  for (int pass = 0; pass < 8; ++pass) {
    const int n_l = pass * 16 + rr;
    const int n = n_wg + n_l;
    int b = n / 9216; int r = n - b * 9216; int h = r / 96; int w = r - h * 96;
    uint2 q0 = *(const uint2*)&lt[n_l * 132 + cc * 8];
    uint2 q1 = *(const uint2*)&lt[n_l * 132 + cc * 8 + 4];
    *(uint4*)(rpad + ((size_t)(b * HP + h + 1) * WP + (w + 1)) * 256 + co_wg + cc * 8) =
        make_uint4(q0.x, q0.y, q1.x, q1.y);
  }
}

// ---------------- conv kernel 4: final conv, relu, NCHW f32 to d_out ------
__global__ __launch_bounds__(256, 2) void k_conv_c2(
    const _Float16* __restrict__ rpad, const _Float16* __restrict__ wc2,
    const float* __restrict__ bias, float* __restrict__ dout)
{
  const int co_wg = blockIdx.x * 128;
  const int n_wg  = blockIdx.y * 128;
  unsigned abase[4], sbase[4]; int co_wv, n_wv, quad, l16;
  conv_setup(co_wg, n_wg, abase, sbase, co_wv, n_wv, quad, l16);

  f32x4 acc[4][4];
#pragma unroll
  for (int i = 0; i < 4; ++i)
#pragma unroll
    for (int j = 0; j < 4; ++j) acc[i][j] = (f32x4){0.f, 0.f, 0.f, 0.f};

  conv_gemm(rpad, wc2, sbase, abase, acc);

  // NCHW writes: lanes (l16) = consecutive w -> coalesced 4B stores
#pragma unroll
  for (int fb = 0; fb < 4; ++fb) {
    int n = n_wg + n_wv + fb * 16 + l16;
    int b = n / 9216; int r = n - b * 9216; int h = r / 96; int w = r - h * 96;
    float* op = dout + (size_t)b * 2359296 + h * 96 + w;
#pragma unroll
    for (int fa = 0; fa < 4; ++fa) {
      int co = co_wg + co_wv + fa * 16 + quad * 4;
      float4 bs = *(const float4*)(bias + co);
      op[(size_t)(co + 0) * 9216] = fmaxf(acc[fa][fb][0] + bs.x, 0.f);
      op[(size_t)(co + 1) * 9216] = fmaxf(acc[fa][fb][1] + bs.y, 0.f);
      op[(size_t)(co + 2) * 9216] = fmaxf(acc[fa][fb][2] + bs.z, 0.f);
      op[(size_t)(co + 3) * 9216] = fmaxf(acc[fa][fb][3] + bs.w, 0.f);
    }
  }
}

// ---------------- aux kernels ---------------------------------------------
__global__ void k_pack_x(const float* __restrict__ x, _Float16* __restrict__ xpad)
{
  __shared__ float tile[32][33];
  const int bh = blockIdx.x;           // b*96+h
  const int b = bh / 96, h = bh - b * 96;
  const int c0 = blockIdx.y * 32, w0 = blockIdx.z * 32;
  const int tx = threadIdx.x & 31, ty = threadIdx.x >> 5;
#pragma unroll
  for (int i = 0; i < 4; ++i) {
    int c = c0 + ty + i * 8;
    tile[ty + i * 8][tx] = x[(((size_t)b * 256 + c) * 96 + h) * 96 + w0 + tx];
  }
  __syncthreads();
#pragma unroll
  for (int i = 0; i < 4; ++i) {
    int w = w0 + ty + i * 8;
    xpad[((size_t)(b * HP + h + 1) * WP + (w + 1)) * 256 + c0 + tx] =
        (_Float16)tile[tx][ty + i * 8];
  }
}

__global__ void k_repack_w(const float* w0, const float* g0, const float* w1, const float* g1,
                           const float* w2, const float* g2, const float* w3, const float* g3,
                           const float* w4, const float* g4, _Float16* __restrict__ wk)
{
  const int set = blockIdx.y;
  const float* w; const float* g;
  switch (set) {
    case 0: w = w0; g = g0; break;
    case 1: w = w1; g = g1; break;
    case 2: w = w2; g = g2; break;
    case 3: w = w3; g = g3; break;
    default: w = w4; g = g4; break;
  }
  const int t = blockIdx.x * 256 + threadIdx.x;   // co*256+ci
  const int co = t >> 8, ci = t & 255;
  const float gv = g[co];
  const float* src = w + ((size_t)co * 256 + ci) * 9;
  _Float16* o = wk + (size_t)set * WSET + (size_t)co * KTOT + ci;
#pragma unroll
  for (int tap = 0; tap < 9; ++tap)
    o[tap * 256] = (_Float16)(src[tap] * gv);
}

__global__ void k_reduce_h(const _Float16* __restrict__ p1, float* __restrict__ u)
{
  const int t = blockIdx.x * 256 + threadIdx.x;   // (b*96+w)*256+c
  const int c = t & 255; const int bw = t >> 8;
  const int b = bw / 96, w = bw - b * 96;
  const _Float16* p = p1 + ((size_t)b * 9216 + w) * 256 + c;
  float m = 0.f;
#pragma unroll 4
  for (int h = 0; h < 96; ++h) m = fmaxf(m, (float)p[(size_t)h * 24576]);
  u[t] = m;
}

__global__ void k_reduce_w(const _Float16* __restrict__ p2, float* __restrict__ v)
{
  const int t = blockIdx.x * 256 + threadIdx.x;   // (b*96+h)*256+c
  const int c = t & 255; const int bh = t >> 8;
  const _Float16* p = p2 + (size_t)bh * 96 * 256 + c;
  float m = 0.f;
#pragma unroll 4
  for (int w = 0; w < 96; ++w) m = fmaxf(m, (float)p[w * 256]);
  v[t] = m;
}

__global__ void k_build_s(const float* __restrict__ u, const float* __restrict__ v,
                          _Float16* __restrict__ spad)
{
  const int bhw = blockIdx.x;                    // b*9216 + h*96 + w
  const int c = threadIdx.x;
  const int b = bhw / 9216; int r = bhw - b * 9216;
  const int h = r / 96, w = r - h * 96;
  float s = u[((size_t)b * 96 + w) * 256 + c] + v[((size_t)b * 96 + h) * 256 + c];
  spad[((size_t)(b * HP + h + 1) * WP + (w + 1)) * 256 + c] = (_Float16)s;
}

// ---------------- launcher -------------------------------------------------
extern "C" void kernel_launch(void* const* d_in, const int* in_sizes, int n_in,
                              void* d_out, int out_size, void* d_ws, size_t ws_size,
                              hipStream_t stream)
{
  const float* x    = (const float*)d_in[0];
  const float* w_p1 = (const float*)d_in[1];
  const float* g_p1 = (const float*)d_in[2];
  const float* b_p1 = (const float*)d_in[3];
  const float* w_p2 = (const float*)d_in[4];
  const float* g_p2 = (const float*)d_in[5];
  const float* b_p2 = (const float*)d_in[6];
  const float* w_p  = (const float*)d_in[7];
  const float* g_p  = (const float*)d_in[8];
  const float* b_p  = (const float*)d_in[9];
  const float* w_c1 = (const float*)d_in[10];
  const float* g_c1 = (const float*)d_in[11];
  const float* b_c1 = (const float*)d_in[12];
  const float* w_c2 = (const float*)d_in[13];
  const float* g_c2 = (const float*)d_in[14];
  const float* b_c2 = (const float*)d_in[15];

  // workspace carve (total ~201 MB)
  char* ws = (char*)d_ws;
  size_t off = 0;
  _Float16* x_pad = (_Float16*)(ws + off); off += XPAD_E * 2;
  _Float16* s_pad = (_Float16*)(ws + off); off += XPAD_E * 2;
  _Float16* r_pad = (_Float16*)(ws + off); off += XPAD_E * 2;
  _Float16* wks   = (_Float16*)(ws + off); off += (size_t)5 * WSET * 2;
  _Float16* p1buf = (_Float16*)(ws + off); off += PBUF_E * 2;
  _Float16* p2buf = (_Float16*)(ws + off); off += PBUF_E * 2;
  float*    u     = (float*)(ws + off);    off += (size_t)UV_E * 4;
  float*    v     = (float*)(ws + off);    off += (size_t)UV_E * 4;
  (void)ws_size; (void)in_sizes; (void)n_in; (void)out_size;

  // zero borders of padded tensors (ws is re-poisoned before every launch)
  hipMemsetAsync(x_pad, 0, XPAD_E * 2, stream);
  hipMemsetAsync(s_pad, 0, XPAD_E * 2, stream);
  hipMemsetAsync(r_pad, 0, XPAD_E * 2, stream);

  k_pack_x  <<<dim3(768, 8, 3), 256, 0, stream>>>(x, x_pad);
  k_repack_w<<<dim3(256, 5),    256, 0, stream>>>(w_p1, g_p1, w_p2, g_p2, w_p, g_p,
                                                  w_c1, g_c1, w_c2, g_c2, wks);
  k_conv_p12<<<dim3(2, 576, 2), 256, 0, stream>>>(x_pad, wks, b_p1, b_p2, p1buf, p2buf);
  k_reduce_h<<<768, 256, 0, stream>>>(p1buf, u);
  k_reduce_w<<<768, 256, 0, stream>>>(p2buf, v);
  k_build_s <<<dim3(73728), 256, 0, stream>>>(u, v, s_pad);
  k_conv_pc1<<<dim3(2, 576), 256, 0, stream>>>(s_pad, x_pad, wks + (size_t)2 * WSET,
                                               wks + (size_t)3 * WSET, b_p, b_c1, r_pad);
  k_conv_c2 <<<dim3(2, 576), 256, 0, stream>>>(r_pad, wks + (size_t)4 * WSET, b_c2,
                                               (float*)d_out);
}

// Round 2
// 1118.040 us; speedup vs baseline: 1.6034x; 1.6034x over previous
//
#include <hip/hip_runtime.h>

// ct_layer: 5x conv3x3(+BN) + corner pools. Round 2: LDS-staged implicit GEMM.
//   - cummax identity: TopPool∘BottomPool = broadcast max over axis.
//   - conv kernels: WG = 128co x (8h x 16w), stage 10x18 halo window per
//     32-ci block into LDS (global_load_lds w=16, double buffered); 9 taps
//     read staged window; A (weights) via per-lane 16B global loads (L2-hot).
//   - XCD swizzle: lin%8 = XCD -> one batch per XCD, co-pair same XCD.

typedef _Float16 f16x8 __attribute__((ext_vector_type(8)));
typedef _Float16 f16x4v __attribute__((ext_vector_type(4)));
typedef float f32x4 __attribute__((ext_vector_type(4)));

#define HP 98
#define WP 98
#define KTOT 2304
#define WSET (256*KTOT)
#define XPAD_E ((size_t)8*HP*WP*256)
#define PBUF_E ((size_t)73728*256)
#define UV_E (8*96*256)

#define BUF_B 12288            // one staged ci-slice: 192 pos * 64B
#define SMEM_B 33792           // max(2*BUF_B, 128*132*2) = epilogue transpose

struct TileCtx {
  unsigned goff[3];            // elem offsets for this thread's 3 stage loads
  unsigned lds_stage;          // byte offset of this thread's t=0 LDS dest
  unsigned aoff;               // elem offset into weight set (lane row+quad)
  int hl, wl, quad;
  int co_wg, co_wv;
  int b, h0, w0;
};

__device__ __forceinline__ TileCtx make_ctx(int lin)
{
  TileCtx c;
  const int g = lin & 7, s = lin >> 3;          // g = nominal XCD
  c.co_wg = (s & 1) * 128;
  const int t = g * 72 + (s >> 1);              // tile 0..575; b == g
  c.b = t / 72;
  const int tt = t - c.b * 72;
  const int ht = tt / 6, wt = tt - ht * 6;
  c.h0 = ht * 8; c.w0 = wt * 16;
  const int tid = threadIdx.x, lane = tid & 63, wv = tid >> 6;
  c.quad = lane >> 4; c.wl = lane & 15;
  c.co_wv = (wv & 1) * 64;
  c.hl = (wv >> 1) * 4;                          // n_wv/16: 0 or 4
  c.aoff = (unsigned)(c.co_wg + c.co_wv + c.wl) * KTOT + c.quad * 8;
  const unsigned base_hw = (unsigned)(c.b * HP + c.h0) * WP + c.w0;
#pragma unroll
  for (int t2 = 0; t2 < 3; ++t2) {
    const int pos = (wv * 3 + t2) * 16 + (lane >> 2);   // 0..191 (180..191 dummy)
    const int wh = pos / 18, ww = pos - wh * 18;
    c.goff[t2] = (base_hw + (unsigned)(wh * WP + ww)) * 256u + (lane & 3) * 8u;
  }
  c.lds_stage = (unsigned)(wv * 3) * 1024u + (unsigned)lane * 16u;
  return c;
}

__device__ __forceinline__ void stage_cb(const _Float16* __restrict__ src,
                                         char* sbuf, const TileCtx& c,
                                         int buf, int cb)
{
  char* l0 = sbuf + buf * BUF_B + c.lds_stage;
#pragma unroll
  for (int t = 0; t < 3; ++t) {
    const _Float16* g = src + c.goff[t] + cb * 32;
    __builtin_amdgcn_global_load_lds(
        (const __attribute__((address_space(1))) void*)g,
        (__attribute__((address_space(3))) void*)(l0 + t * 1024), 16, 0, 0);
  }
}

// One full conv accumulation (K = 9 taps x 256 ci) into acc[4][4].
__device__ __forceinline__ void conv_accum(const _Float16* __restrict__ src,
                                           const _Float16* __restrict__ wk,
                                           char* sbuf, const TileCtx& c,
                                           f32x4 acc[4][4])
{
  const _Float16* A0 = wk + c.aoff;
  stage_cb(src, sbuf, c, 0, 0);
#pragma unroll 1
  for (int cb = 0; cb < 8; ++cb) {
    __syncthreads();                               // staged buf[cb&1] ready
    if (cb < 7) stage_cb(src, sbuf, c, (cb + 1) & 1, cb + 1);
    const _Float16* B = (const _Float16*)(sbuf + (cb & 1) * BUF_B);
    const _Float16* A = A0 + cb * 32;
    const int bbase = (c.hl * 18 + c.wl) * 32 + c.quad * 8;
#pragma unroll
    for (int tap = 0; tap < 9; ++tap) {
      const int dh = tap / 3, dw = tap - dh * 3;
      f16x8 af[4], bf[4];
#pragma unroll
      for (int i = 0; i < 4; ++i)
        af[i] = *(const f16x8*)(A + tap * 256 + i * (16 * KTOT));
#pragma unroll
      for (int j = 0; j < 4; ++j)
        bf[j] = *(const f16x8*)(B + bbase + ((j + dh) * 18 + dw) * 32);
#pragma unroll
      for (int i = 0; i < 4; ++i)
#pragma unroll
        for (int j = 0; j < 4; ++j)
          acc[i][j] = __builtin_amdgcn_mfma_f32_16x16x32_f16(af[i], bf[j], acc[i][j], 0, 0, 0);
    }
  }
  __syncthreads();                                 // sbuf free for reuse
}

// Epilogue: bias(+bias2)+relu -> f16, LDS transpose, coalesced NHWC stores.
__device__ __forceinline__ void epilogue_f16(const f32x4 acc[4][4],
                                             const float* __restrict__ bias,
                                             const float* __restrict__ bias2,
                                             char* smem, const TileCtx& c,
                                             _Float16* out_base, int rstride)
{
  _Float16* lt = (_Float16*)smem;
#pragma unroll
  for (int fa = 0; fa < 4; ++fa) {
    const int co_l = c.co_wv + fa * 16 + c.quad * 4;
    float4 bs = *(const float4*)(bias + c.co_wg + co_l);
    if (bias2) {
      const float4 b2 = *(const float4*)(bias2 + c.co_wg + co_l);
      bs.x += b2.x; bs.y += b2.y; bs.z += b2.z; bs.w += b2.w;
    }
#pragma unroll
    for (int fb = 0; fb < 4; ++fb) {
      const int n_l = (c.hl + fb) * 16 + c.wl;
      f16x4v pk;
      pk[0] = (_Float16)fmaxf(acc[fa][fb][0] + bs.x, 0.f);
      pk[1] = (_Float16)fmaxf(acc[fa][fb][1] + bs.y, 0.f);
      pk[2] = (_Float16)fmaxf(acc[fa][fb][2] + bs.z, 0.f);
      pk[3] = (_Float16)fmaxf(acc[fa][fb][3] + bs.w, 0.f);
      *(f16x4v*)&lt[n_l * 132 + co_l] = pk;
    }
  }
  __syncthreads();
  const int cc = threadIdx.x & 15, rr = threadIdx.x >> 4;
#pragma unroll
  for (int pass = 0; pass < 8; ++pass) {
    const int n_l = pass * 16 + rr;                // hl = pass, wl = rr
    uint2 q0 = *(const uint2*)&lt[n_l * 132 + cc * 8];
    uint2 q1 = *(const uint2*)&lt[n_l * 132 + cc * 8 + 4];
    *(uint4*)(out_base + (size_t)pass * rstride + rr * 256 + c.co_wg + cc * 8) =
        make_uint4(q0.x, q0.y, q1.x, q1.y);
  }
}

// ---------------- conv kernels --------------------------------------------
__global__ __launch_bounds__(256, 2) void k_conv_p12(
    const _Float16* __restrict__ xpad, const _Float16* __restrict__ wk,
    const float* __restrict__ bias1, const float* __restrict__ bias2,
    _Float16* __restrict__ p1, _Float16* __restrict__ p2)
{
  __shared__ __align__(16) char smem[SMEM_B];
  TileCtx c = make_ctx(blockIdx.x);
  const int br = blockIdx.z;
  f32x4 acc[4][4];
#pragma unroll
  for (int i = 0; i < 4; ++i)
#pragma unroll
    for (int j = 0; j < 4; ++j) acc[i][j] = (f32x4){0.f, 0.f, 0.f, 0.f};
  conv_accum(xpad, wk + (size_t)br * WSET, smem, c, acc);
  _Float16* out = (br ? p2 : p1) + ((size_t)(c.b * 96 + c.h0) * 96 + c.w0) * 256;
  epilogue_f16(acc, br ? bias2 : bias1, nullptr, smem, c, out, 96 * 256);
}

__global__ __launch_bounds__(256, 2) void k_conv_pc1(
    const _Float16* __restrict__ spad, const _Float16* __restrict__ xpad,
    const _Float16* __restrict__ wp, const _Float16* __restrict__ wc1,
    const float* __restrict__ bias_p, const float* __restrict__ bias_c1,
    _Float16* __restrict__ rpad)
{
  __shared__ __align__(16) char smem[SMEM_B];
  TileCtx c = make_ctx(blockIdx.x);
  f32x4 acc[4][4];
#pragma unroll
  for (int i = 0; i < 4; ++i)
#pragma unroll
    for (int j = 0; j < 4; ++j) acc[i][j] = (f32x4){0.f, 0.f, 0.f, 0.f};
  conv_accum(spad, wp,  smem, c, acc);
  conv_accum(xpad, wc1, smem, c, acc);
  _Float16* out = rpad + ((size_t)(c.b * HP + c.h0 + 1) * WP + c.w0 + 1) * 256;
  epilogue_f16(acc, bias_p, bias_c1, smem, c, out, WP * 256);
}

__global__ __launch_bounds__(256, 2) void k_conv_c2(
    const _Float16* __restrict__ rpad, const _Float16* __restrict__ wc2,
    const float* __restrict__ bias, float* __restrict__ dout)
{
  __shared__ __align__(16) char smem[SMEM_B];
  TileCtx c = make_ctx(blockIdx.x);
  f32x4 acc[4][4];
#pragma unroll
  for (int i = 0; i < 4; ++i)
#pragma unroll
    for (int j = 0; j < 4; ++j) acc[i][j] = (f32x4){0.f, 0.f, 0.f, 0.f};
  conv_accum(rpad, wc2, smem, c, acc);
  // NCHW f32 stores: lanes (wl) = consecutive w
#pragma unroll
  for (int fb = 0; fb < 4; ++fb) {
    const int h = c.h0 + c.hl + fb;
    const int w = c.w0 + c.wl;
    float* op = dout + (size_t)c.b * 2359296 + h * 96 + w;
#pragma unroll
    for (int fa = 0; fa < 4; ++fa) {
      const int co = c.co_wg + c.co_wv + fa * 16 + c.quad * 4;
      const float4 bs = *(const float4*)(bias + co);
      op[(size_t)(co + 0) * 9216] = fmaxf(acc[fa][fb][0] + bs.x, 0.f);
      op[(size_t)(co + 1) * 9216] = fmaxf(acc[fa][fb][1] + bs.y, 0.f);
      op[(size_t)(co + 2) * 9216] = fmaxf(acc[fa][fb][2] + bs.z, 0.f);
      op[(size_t)(co + 3) * 9216] = fmaxf(acc[fa][fb][3] + bs.w, 0.f);
    }
  }
}

// ---------------- aux kernels (unchanged from round 1) --------------------
__global__ void k_pack_x(const float* __restrict__ x, _Float16* __restrict__ xpad)
{
  __shared__ float tile[32][33];
  const int bh = blockIdx.x;
  const int b = bh / 96, h = bh - b * 96;
  const int c0 = blockIdx.y * 32, w0 = blockIdx.z * 32;
  const int tx = threadIdx.x & 31, ty = threadIdx.x >> 5;
#pragma unroll
  for (int i = 0; i < 4; ++i) {
    int cI = c0 + ty + i * 8;
    tile[ty + i * 8][tx] = x[(((size_t)b * 256 + cI) * 96 + h) * 96 + w0 + tx];
  }
  __syncthreads();
#pragma unroll
  for (int i = 0; i < 4; ++i) {
    int w = w0 + ty + i * 8;
    xpad[((size_t)(b * HP + h + 1) * WP + (w + 1)) * 256 + c0 + tx] =
        (_Float16)tile[tx][ty + i * 8];
  }
}

__global__ void k_repack_w(const float* w0, const float* g0, const float* w1, const float* g1,
                           const float* w2, const float* g2, const float* w3, const float* g3,
                           const float* w4, const float* g4, _Float16* __restrict__ wk)
{
  const int set = blockIdx.y;
  const float* w; const float* g;
  switch (set) {
    case 0: w = w0; g = g0; break;
    case 1: w = w1; g = g1; break;
    case 2: w = w2; g = g2; break;
    case 3: w = w3; g = g3; break;
    default: w = w4; g = g4; break;
  }
  const int t = blockIdx.x * 256 + threadIdx.x;
  const int co = t >> 8, ci = t & 255;
  const float gv = g[co];
  const float* src = w + ((size_t)co * 256 + ci) * 9;
  _Float16* o = wk + (size_t)set * WSET + (size_t)co * KTOT + ci;
#pragma unroll
  for (int tap = 0; tap < 9; ++tap)
    o[tap * 256] = (_Float16)(src[tap] * gv);
}

__global__ void k_reduce_h(const _Float16* __restrict__ p1, float* __restrict__ u)
{
  const int t = blockIdx.x * 256 + threadIdx.x;
  const int c = t & 255; const int bw = t >> 8;
  const int b = bw / 96, w = bw - b * 96;
  const _Float16* p = p1 + ((size_t)b * 9216 + w) * 256 + c;
  float m = 0.f;
#pragma unroll 4
  for (int h = 0; h < 96; ++h) m = fmaxf(m, (float)p[(size_t)h * 24576]);
  u[t] = m;
}

__global__ void k_reduce_w(const _Float16* __restrict__ p2, float* __restrict__ v)
{
  const int t = blockIdx.x * 256 + threadIdx.x;
  const int c = t & 255; const int bh = t >> 8;
  const _Float16* p = p2 + (size_t)bh * 96 * 256 + c;
  float m = 0.f;
#pragma unroll 4
  for (int w = 0; w < 96; ++w) m = fmaxf(m, (float)p[w * 256]);
  v[t] = m;
}

__global__ void k_build_s(const float* __restrict__ u, const float* __restrict__ v,
                          _Float16* __restrict__ spad)
{
  const int bhw = blockIdx.x;
  const int c = threadIdx.x;
  const int b = bhw / 9216; int r = bhw - b * 9216;
  const int h = r / 96, w = r - h * 96;
  float s = u[((size_t)b * 96 + w) * 256 + c] + v[((size_t)b * 96 + h) * 256 + c];
  spad[((size_t)(b * HP + h + 1) * WP + (w + 1)) * 256 + c] = (_Float16)s;
}

// ---------------- launcher -------------------------------------------------
extern "C" void kernel_launch(void* const* d_in, const int* in_sizes, int n_in,
                              void* d_out, int out_size, void* d_ws, size_t ws_size,
                              hipStream_t stream)
{
  const float* x    = (const float*)d_in[0];
  const float* w_p1 = (const float*)d_in[1];
  const float* g_p1 = (const float*)d_in[2];
  const float* b_p1 = (const float*)d_in[3];
  const float* w_p2 = (const float*)d_in[4];
  const float* g_p2 = (const float*)d_in[5];
  const float* b_p2 = (const float*)d_in[6];
  const float* w_p  = (const float*)d_in[7];
  const float* g_p  = (const float*)d_in[8];
  const float* b_p  = (const float*)d_in[9];
  const float* w_c1 = (const float*)d_in[10];
  const float* g_c1 = (const float*)d_in[11];
  const float* b_c1 = (const float*)d_in[12];
  const float* w_c2 = (const float*)d_in[13];
  const float* g_c2 = (const float*)d_in[14];
  const float* b_c2 = (const float*)d_in[15];

  char* ws = (char*)d_ws;
  size_t off = 0;
  _Float16* x_pad = (_Float16*)(ws + off); off += XPAD_E * 2;
  _Float16* s_pad = (_Float16*)(ws + off); off += XPAD_E * 2;
  _Float16* r_pad = (_Float16*)(ws + off); off += XPAD_E * 2;
  _Float16* wks   = (_Float16*)(ws + off); off += (size_t)5 * WSET * 2;
  _Float16* p1buf = (_Float16*)(ws + off); off += PBUF_E * 2;
  _Float16* p2buf = (_Float16*)(ws + off); off += PBUF_E * 2;
  float*    u     = (float*)(ws + off);    off += (size_t)UV_E * 4;
  float*    v     = (float*)(ws + off);    off += (size_t)UV_E * 4;
  (void)ws_size; (void)in_sizes; (void)n_in; (void)out_size;

  hipMemsetAsync(x_pad, 0, XPAD_E * 2, stream);
  hipMemsetAsync(s_pad, 0, XPAD_E * 2, stream);
  hipMemsetAsync(r_pad, 0, XPAD_E * 2, stream);

  k_pack_x  <<<dim3(768, 8, 3), 256, 0, stream>>>(x, x_pad);
  k_repack_w<<<dim3(256, 5),    256, 0, stream>>>(w_p1, g_p1, w_p2, g_p2, w_p, g_p,
                                                  w_c1, g_c1, w_c2, g_c2, wks);
  k_conv_p12<<<dim3(1152, 1, 2), 256, 0, stream>>>(x_pad, wks, b_p1, b_p2, p1buf, p2buf);
  k_reduce_h<<<768, 256, 0, stream>>>(p1buf, u);
  k_reduce_w<<<768, 256, 0, stream>>>(p2buf, v);
  k_build_s <<<dim3(73728), 256, 0, stream>>>(u, v, s_pad);
  k_conv_pc1<<<1152, 256, 0, stream>>>(s_pad, x_pad, wks + (size_t)2 * WSET,
                                       wks + (size_t)3 * WSET, b_p, b_c1, r_pad);
  k_conv_c2 <<<1152, 256, 0, stream>>>(r_pad, wks + (size_t)4 * WSET, b_c2,
                                       (float*)d_out);
}

// Round 3
// 705.052 us; speedup vs baseline: 2.5426x; 1.5858x over previous
//
#include <hip/hip_runtime.h>

// ct_layer: 5x conv3x3(+BN) + corner pools. Round 3: coalesced weight tiles.
//   - cummax identity: TopPool∘BottomPool = broadcast max over axis.
//   - conv kernels: WG = 128co x (8h x 16w); B staged per 32-ci block into
//     LDS (global_load_lds w=16, double buffered); A (weights) repacked into
//     MFMA-tile-contiguous layout [cb][tap][cog][m16][k32] -> each fragment
//     load is one coalesced 1KB wave burst.
//   - tap loop dw-outer: 6 LDS rows cached in regs, reused across dh
//     (18 ds_read_b128 per cb instead of 36).

typedef _Float16 f16x8 __attribute__((ext_vector_type(8)));
typedef _Float16 f16x4v __attribute__((ext_vector_type(4)));
typedef float f32x4 __attribute__((ext_vector_type(4)));

#define HP 98
#define WP 98
#define KTOT 2304
#define WSET (256*KTOT)                // 8*9*16*512 = 589824 elems
#define XPAD_E ((size_t)8*HP*WP*256)
#define PBUF_E ((size_t)73728*256)
#define UV_E (8*96*256)

#define BUF_B 12288            // one staged ci-slice: 192 pos * 64B
#define SMEM_B 33792           // max(2*BUF_B, 128*132*2)

struct TileCtx {
  unsigned goff[3];            // elem offsets for this thread's 3 stage loads
  unsigned lds_stage;          // byte offset of this thread's t=0 LDS dest
  unsigned aoff;               // elem offset into weight set (tile layout)
  int hl, wl, quad;
  int co_wg, co_wv;
  int b, h0, w0;
};

__device__ __forceinline__ TileCtx make_ctx(int lin)
{
  TileCtx c;
  const int g = lin & 7, s = lin >> 3;          // g = nominal XCD, b == g
  c.co_wg = (s & 1) * 128;
  const int t = g * 72 + (s >> 1);
  c.b = t / 72;
  const int tt = t - c.b * 72;
  const int ht = tt / 6, wt = tt - ht * 6;
  c.h0 = ht * 8; c.w0 = wt * 16;
  const int tid = threadIdx.x, lane = tid & 63, wv = tid >> 6;
  c.quad = lane >> 4; c.wl = lane & 15;
  c.co_wv = (wv & 1) * 64;
  c.hl = (wv >> 1) * 4;
  // tiled weight layout: idx = ((cb*9+tap)*16 + cog)*512 + m*32 + kk
  c.aoff = (unsigned)(((c.co_wg + c.co_wv) >> 4) * 512 + c.wl * 32 + c.quad * 8);
  const unsigned base_hw = (unsigned)(c.b * HP + c.h0) * WP + c.w0;
#pragma unroll
  for (int t2 = 0; t2 < 3; ++t2) {
    const int pos = (wv * 3 + t2) * 16 + (lane >> 2);   // 0..191 (180..191 dummy)
    const int wh = pos / 18, ww = pos - wh * 18;
    c.goff[t2] = (base_hw + (unsigned)(wh * WP + ww)) * 256u + (lane & 3) * 8u;
  }
  c.lds_stage = (unsigned)(wv * 3) * 1024u + (unsigned)lane * 16u;
  return c;
}

__device__ __forceinline__ void stage_cb(const _Float16* __restrict__ src,
                                         char* sbuf, const TileCtx& c,
                                         int buf, int cb)
{
  char* l0 = sbuf + buf * BUF_B + c.lds_stage;
#pragma unroll
  for (int t = 0; t < 3; ++t) {
    const _Float16* g = src + c.goff[t] + cb * 32;
    __builtin_amdgcn_global_load_lds(
        (const __attribute__((address_space(1))) void*)g,
        (__attribute__((address_space(3))) void*)(l0 + t * 1024), 16, 0, 0);
  }
}

// One full conv accumulation (K = 9 taps x 256 ci) into acc[4][4].
__device__ __forceinline__ void conv_accum(const _Float16* __restrict__ src,
                                           const _Float16* __restrict__ wk,
                                           char* sbuf, const TileCtx& c,
                                           f32x4 acc[4][4])
{
  const _Float16* A0 = wk + c.aoff;
  const int rbase = (c.hl * 18 + c.wl) * 32 + c.quad * 8;
  stage_cb(src, sbuf, c, 0, 0);
#pragma unroll 1
  for (int cb = 0; cb < 8; ++cb) {
    __syncthreads();                               // staged buf[cb&1] ready
    if (cb < 7) stage_cb(src, sbuf, c, (cb + 1) & 1, cb + 1);
    const _Float16* B = (const _Float16*)(sbuf + (cb & 1) * BUF_B);
    const _Float16* A = A0 + cb * (9 * 8192);
#pragma unroll
    for (int dw = 0; dw < 3; ++dw) {
      f16x8 row[6];
#pragma unroll
      for (int r = 0; r < 6; ++r)
        row[r] = *(const f16x8*)(B + rbase + (r * 18 + dw) * 32);
#pragma unroll
      for (int dh = 0; dh < 3; ++dh) {
        f16x8 af[4];
#pragma unroll
        for (int i = 0; i < 4; ++i)
          af[i] = *(const f16x8*)(A + (dh * 3 + dw) * 8192 + i * 512);
#pragma unroll
        for (int i = 0; i < 4; ++i)
#pragma unroll
          for (int j = 0; j < 4; ++j)
            acc[i][j] = __builtin_amdgcn_mfma_f32_16x16x32_f16(af[i], row[j + dh], acc[i][j], 0, 0, 0);
      }
    }
  }
  __syncthreads();                                 // sbuf free for reuse
}

// Epilogue: bias(+bias2)+relu -> f16, LDS transpose, coalesced NHWC stores.
__device__ __forceinline__ void epilogue_f16(const f32x4 acc[4][4],
                                             const float* __restrict__ bias,
                                             const float* __restrict__ bias2,
                                             char* smem, const TileCtx& c,
                                             _Float16* out_base, int rstride)
{
  _Float16* lt = (_Float16*)smem;
#pragma unroll
  for (int fa = 0; fa < 4; ++fa) {
    const int co_l = c.co_wv + fa * 16 + c.quad * 4;
    float4 bs = *(const float4*)(bias + c.co_wg + co_l);
    if (bias2) {
      const float4 b2 = *(const float4*)(bias2 + c.co_wg + co_l);
      bs.x += b2.x; bs.y += b2.y; bs.z += b2.z; bs.w += b2.w;
    }
#pragma unroll
    for (int fb = 0; fb < 4; ++fb) {
      const int n_l = (c.hl + fb) * 16 + c.wl;
      f16x4v pk;
      pk[0] = (_Float16)fmaxf(acc[fa][fb][0] + bs.x, 0.f);
      pk[1] = (_Float16)fmaxf(acc[fa][fb][1] + bs.y, 0.f);
      pk[2] = (_Float16)fmaxf(acc[fa][fb][2] + bs.z, 0.f);
      pk[3] = (_Float16)fmaxf(acc[fa][fb][3] + bs.w, 0.f);
      *(f16x4v*)&lt[n_l * 132 + co_l] = pk;
    }
  }
  __syncthreads();
  const int cc = threadIdx.x & 15, rr = threadIdx.x >> 4;
#pragma unroll
  for (int pass = 0; pass < 8; ++pass) {
    const int n_l = pass * 16 + rr;
    uint2 q0 = *(const uint2*)&lt[n_l * 132 + cc * 8];
    uint2 q1 = *(const uint2*)&lt[n_l * 132 + cc * 8 + 4];
    *(uint4*)(out_base + (size_t)pass * rstride + rr * 256 + c.co_wg + cc * 8) =
        make_uint4(q0.x, q0.y, q1.x, q1.y);
  }
}

// ---------------- conv kernels --------------------------------------------
__global__ __launch_bounds__(256, 2) void k_conv_p12(
    const _Float16* __restrict__ xpad, const _Float16* __restrict__ wk,
    const float* __restrict__ bias1, const float* __restrict__ bias2,
    _Float16* __restrict__ p1, _Float16* __restrict__ p2)
{
  __shared__ __align__(16) char smem[SMEM_B];
  TileCtx c = make_ctx(blockIdx.x);
  const int br = blockIdx.z;
  f32x4 acc[4][4];
#pragma unroll
  for (int i = 0; i < 4; ++i)
#pragma unroll
    for (int j = 0; j < 4; ++j) acc[i][j] = (f32x4){0.f, 0.f, 0.f, 0.f};
  conv_accum(xpad, wk + (size_t)br * WSET, smem, c, acc);
  _Float16* out = (br ? p2 : p1) + ((size_t)(c.b * 96 + c.h0) * 96 + c.w0) * 256;
  epilogue_f16(acc, br ? bias2 : bias1, nullptr, smem, c, out, 96 * 256);
}

__global__ __launch_bounds__(256, 2) void k_conv_pc1(
    const _Float16* __restrict__ spad, const _Float16* __restrict__ xpad,
    const _Float16* __restrict__ wp, const _Float16* __restrict__ wc1,
    const float* __restrict__ bias_p, const float* __restrict__ bias_c1,
    _Float16* __restrict__ rpad)
{
  __shared__ __align__(16) char smem[SMEM_B];
  TileCtx c = make_ctx(blockIdx.x);
  f32x4 acc[4][4];
#pragma unroll
  for (int i = 0; i < 4; ++i)
#pragma unroll
    for (int j = 0; j < 4; ++j) acc[i][j] = (f32x4){0.f, 0.f, 0.f, 0.f};
  conv_accum(spad, wp,  smem, c, acc);
  conv_accum(xpad, wc1, smem, c, acc);
  _Float16* out = rpad + ((size_t)(c.b * HP + c.h0 + 1) * WP + c.w0 + 1) * 256;
  epilogue_f16(acc, bias_p, bias_c1, smem, c, out, WP * 256);
}

__global__ __launch_bounds__(256, 2) void k_conv_c2(
    const _Float16* __restrict__ rpad, const _Float16* __restrict__ wc2,
    const float* __restrict__ bias, float* __restrict__ dout)
{
  __shared__ __align__(16) char smem[SMEM_B];
  TileCtx c = make_ctx(blockIdx.x);
  f32x4 acc[4][4];
#pragma unroll
  for (int i = 0; i < 4; ++i)
#pragma unroll
    for (int j = 0; j < 4; ++j) acc[i][j] = (f32x4){0.f, 0.f, 0.f, 0.f};
  conv_accum(rpad, wc2, smem, c, acc);
  // NCHW f32 stores: lanes (wl) = consecutive w
#pragma unroll
  for (int fb = 0; fb < 4; ++fb) {
    const int h = c.h0 + c.hl + fb;
    const int w = c.w0 + c.wl;
    float* op = dout + (size_t)c.b * 2359296 + h * 96 + w;
#pragma unroll
    for (int fa = 0; fa < 4; ++fa) {
      const int co = c.co_wg + c.co_wv + fa * 16 + c.quad * 4;
      const float4 bs = *(const float4*)(bias + co);
      op[(size_t)(co + 0) * 9216] = fmaxf(acc[fa][fb][0] + bs.x, 0.f);
      op[(size_t)(co + 1) * 9216] = fmaxf(acc[fa][fb][1] + bs.y, 0.f);
      op[(size_t)(co + 2) * 9216] = fmaxf(acc[fa][fb][2] + bs.z, 0.f);
      op[(size_t)(co + 3) * 9216] = fmaxf(acc[fa][fb][3] + bs.w, 0.f);
    }
  }
}

// ---------------- aux kernels ---------------------------------------------
__global__ void k_pack_x(const float* __restrict__ x, _Float16* __restrict__ xpad)
{
  __shared__ float tile[32][33];
  const int bh = blockIdx.x;
  const int b = bh / 96, h = bh - b * 96;
  const int c0 = blockIdx.y * 32, w0 = blockIdx.z * 32;
  const int tx = threadIdx.x & 31, ty = threadIdx.x >> 5;
#pragma unroll
  for (int i = 0; i < 4; ++i) {
    int cI = c0 + ty + i * 8;
    tile[ty + i * 8][tx] = x[(((size_t)b * 256 + cI) * 96 + h) * 96 + w0 + tx];
  }
  __syncthreads();
#pragma unroll
  for (int i = 0; i < 4; ++i) {
    int w = w0 + ty + i * 8;
    xpad[((size_t)(b * HP + h + 1) * WP + (w + 1)) * 256 + c0 + tx] =
        (_Float16)tile[tx][ty + i * 8];
  }
}

// repack into tiled layout: idx = ((cb*9+tap)*16 + cog)*512 + m*32 + kk
__global__ void k_repack_w(const float* w0, const float* g0, const float* w1, const float* g1,
                           const float* w2, const float* g2, const float* w3, const float* g3,
                           const float* w4, const float* g4, _Float16* __restrict__ wk)
{
  const int set = blockIdx.y;
  const float* w; const float* g;
  switch (set) {
    case 0: w = w0; g = g0; break;
    case 1: w = w1; g = g1; break;
    case 2: w = w2; g = g2; break;
    case 3: w = w3; g = g3; break;
    default: w = w4; g = g4; break;
  }
  const int t = blockIdx.x * 256 + threadIdx.x;   // co*256 + ci
  const int co = t >> 8, ci = t & 255;
  const int cb = ci >> 5, kk = ci & 31, cog = co >> 4, m = co & 15;
  const float gv = g[co];
  const float* src = w + ((size_t)co * 256 + ci) * 9;
  _Float16* dst = wk + (size_t)set * WSET + cog * 512 + m * 32 + kk;
#pragma unroll
  for (int tap = 0; tap < 9; ++tap)
    dst[(cb * 9 + tap) * 8192] = (_Float16)(src[tap] * gv);
}

__global__ void k_reduce_h(const _Float16* __restrict__ p1, float* __restrict__ u)
{
  const int t = blockIdx.x * 256 + threadIdx.x;
  const int c = t & 255; const int bw = t >> 8;
  const int b = bw / 96, w = bw - b * 96;
  const _Float16* p = p1 + ((size_t)b * 9216 + w) * 256 + c;
  float m = 0.f;
#pragma unroll 4
  for (int h = 0; h < 96; ++h) m = fmaxf(m, (float)p[(size_t)h * 24576]);
  u[t] = m;
}

__global__ void k_reduce_w(const _Float16* __restrict__ p2, float* __restrict__ v)
{
  const int t = blockIdx.x * 256 + threadIdx.x;
  const int c = t & 255; const int bh = t >> 8;
  const _Float16* p = p2 + (size_t)bh * 96 * 256 + c;
  float m = 0.f;
#pragma unroll 4
  for (int w = 0; w < 96; ++w) m = fmaxf(m, (float)p[w * 256]);
  v[t] = m;
}

__global__ void k_build_s(const float* __restrict__ u, const float* __restrict__ v,
                          _Float16* __restrict__ spad)
{
  const int bhw = blockIdx.x;
  const int c = threadIdx.x;
  const int b = bhw / 9216; int r = bhw - b * 9216;
  const int h = r / 96, w = r - h * 96;
  float s = u[((size_t)b * 96 + w) * 256 + c] + v[((size_t)b * 96 + h) * 256 + c];
  spad[((size_t)(b * HP + h + 1) * WP + (w + 1)) * 256 + c] = (_Float16)s;
}

// ---------------- launcher -------------------------------------------------
extern "C" void kernel_launch(void* const* d_in, const int* in_sizes, int n_in,
                              void* d_out, int out_size, void* d_ws, size_t ws_size,
                              hipStream_t stream)
{
  const float* x    = (const float*)d_in[0];
  const float* w_p1 = (const float*)d_in[1];
  const float* g_p1 = (const float*)d_in[2];
  const float* b_p1 = (const float*)d_in[3];
  const float* w_p2 = (const float*)d_in[4];
  const float* g_p2 = (const float*)d_in[5];
  const float* b_p2 = (const float*)d_in[6];
  const float* w_p  = (const float*)d_in[7];
  const float* g_p  = (const float*)d_in[8];
  const float* b_p  = (const float*)d_in[9];
  const float* w_c1 = (const float*)d_in[10];
  const float* g_c1 = (const float*)d_in[11];
  const float* b_c1 = (const float*)d_in[12];
  const float* w_c2 = (const float*)d_in[13];
  const float* g_c2 = (const float*)d_in[14];
  const float* b_c2 = (const float*)d_in[15];

  char* ws = (char*)d_ws;
  size_t off = 0;
  _Float16* x_pad = (_Float16*)(ws + off); off += XPAD_E * 2;
  _Float16* s_pad = (_Float16*)(ws + off); off += XPAD_E * 2;
  _Float16* r_pad = (_Float16*)(ws + off); off += XPAD_E * 2;
  _Float16* wks   = (_Float16*)(ws + off); off += (size_t)5 * WSET * 2;
  _Float16* p1buf = (_Float16*)(ws + off); off += PBUF_E * 2;
  _Float16* p2buf = (_Float16*)(ws + off); off += PBUF_E * 2;
  float*    u     = (float*)(ws + off);    off += (size_t)UV_E * 4;
  float*    v     = (float*)(ws + off);    off += (size_t)UV_E * 4;
  (void)ws_size; (void)in_sizes; (void)n_in; (void)out_size;

  hipMemsetAsync(x_pad, 0, XPAD_E * 2, stream);
  hipMemsetAsync(s_pad, 0, XPAD_E * 2, stream);
  hipMemsetAsync(r_pad, 0, XPAD_E * 2, stream);

  k_pack_x  <<<dim3(768, 8, 3), 256, 0, stream>>>(x, x_pad);
  k_repack_w<<<dim3(256, 5),    256, 0, stream>>>(w_p1, g_p1, w_p2, g_p2, w_p, g_p,
                                                  w_c1, g_c1, w_c2, g_c2, wks);
  k_conv_p12<<<dim3(1152, 1, 2), 256, 0, stream>>>(x_pad, wks, b_p1, b_p2, p1buf, p2buf);
  k_reduce_h<<<768, 256, 0, stream>>>(p1buf, u);
  k_reduce_w<<<768, 256, 0, stream>>>(p2buf, v);
  k_build_s <<<dim3(73728), 256, 0, stream>>>(u, v, s_pad);
  k_conv_pc1<<<1152, 256, 0, stream>>>(s_pad, x_pad, wks + (size_t)2 * WSET,
                                       wks + (size_t)3 * WSET, b_p, b_c1, r_pad);
  k_conv_c2 <<<1152, 256, 0, stream>>>(r_pad, wks + (size_t)4 * WSET, b_c2,
                                       (float*)d_out);
}